// Round 2
// baseline (239.560 us; speedup 1.0000x reference)
//
#include <hip/hip_runtime.h>

#define B  16
#define S  4096
#define R  512          // LORA_RANK
#define QR 1536         // Q_LORA_RANK
#define H  32
#define D  128
#define HD 4096         // H*D

// ---------------------------------------------------------------------------
// Kernel A: q[b,o] = hsq[b,:] . Wq[o,:] + bq[o]
// grid 256 x 512 threads; full hsq (96 KiB) in LDS; each wave handles 2 rows.
// ---------------------------------------------------------------------------
__global__ __launch_bounds__(512) void k_q(const float* __restrict__ hsq,
                                           const float* __restrict__ Wq,
                                           const float* __restrict__ bq,
                                           float* __restrict__ q) {
  __shared__ float hs[B * QR];  // 96 KiB
  int tid = threadIdx.x;
  for (int idx = tid * 4; idx < B * QR; idx += 2048)
    *(float4*)&hs[idx] = *(const float4*)&hsq[idx];
  __syncthreads();

  int wave = tid >> 6, lane = tid & 63;
  int o = blockIdx.x * 16 + wave * 2;

  float acc0[B], acc1[B];
#pragma unroll
  for (int b = 0; b < B; ++b) { acc0[b] = 0.f; acc1[b] = 0.f; }

  const float* w0r = Wq + (size_t)o * QR;
  const float* w1r = w0r + QR;
  for (int k = lane * 4; k < QR; k += 256) {
    float4 wa = *(const float4*)&w0r[k];
    float4 wb = *(const float4*)&w1r[k];
#pragma unroll
    for (int b = 0; b < B; ++b) {
      float4 h4 = *(const float4*)&hs[b * QR + k];
      acc0[b] += wa.x * h4.x + wa.y * h4.y + wa.z * h4.z + wa.w * h4.w;
      acc1[b] += wb.x * h4.x + wb.y * h4.y + wb.z * h4.z + wb.w * h4.w;
    }
  }
#pragma unroll
  for (int b = 0; b < B; ++b) {
    float v0 = acc0[b], v1 = acc1[b];
#pragma unroll
    for (int off = 32; off > 0; off >>= 1) {
      v0 += __shfl_xor(v0, off);
      v1 += __shfl_xor(v1, off);
    }
    if (lane == 0) {
      q[b * HD + o]     = v0 + bq[o];
      q[b * HD + o + 1] = v1 + bq[o + 1];
    }
  }
}

// ---------------------------------------------------------------------------
// Kernel B: qhat[b,h,r] = sum_d q[b, h*D+d] * Wkv[h*D+d, r]
// grid (32 h, 8 r-chunks) x 256
// ---------------------------------------------------------------------------
__global__ __launch_bounds__(256) void k_qhat(const float* __restrict__ q,
                                              const float* __restrict__ Wkv,
                                              float* __restrict__ qhat) {
  int h = blockIdx.x;
  int r0 = blockIdx.y * 64;
  __shared__ float qs[B][D];  // 8 KiB
  int tid = threadIdx.x;
  for (int idx = tid; idx < B * D; idx += 256) {
    int b = idx >> 7, d = idx & (D - 1);
    qs[b][d] = q[b * HD + h * D + d];
  }
  __syncthreads();

  int r_l = tid & 63, bg = tid >> 6;
  float acc[4] = {0.f, 0.f, 0.f, 0.f};
  const float* wbase = Wkv + (size_t)(h * D) * R + r0 + r_l;
  for (int d = 0; d < D; d += 4) {
    float w0 = wbase[(d + 0) * R];
    float w1 = wbase[(d + 1) * R];
    float w2 = wbase[(d + 2) * R];
    float w3 = wbase[(d + 3) * R];
#pragma unroll
    for (int i = 0; i < 4; ++i) {
      float4 q4 = *(const float4*)&qs[bg * 4 + i][d];
      acc[i] += q4.x * w0 + q4.y * w1 + q4.z * w2 + q4.w * w3;
    }
  }
#pragma unroll
  for (int i = 0; i < 4; ++i)
    qhat[((size_t)(bg * 4 + i) * H + h) * R + r0 + r_l] = acc[i];
}

// ---------------------------------------------------------------------------
// Kernel qb: qb[b,h] = sum_d q[b,h,d] * bkv[h*D+d]
// ---------------------------------------------------------------------------
__global__ __launch_bounds__(256) void k_qb(const float* __restrict__ q,
                                            const float* __restrict__ bkv,
                                            float* __restrict__ qb) {
  int idx = blockIdx.x * 256 + threadIdx.x;  // 0..511
  int b = idx >> 5, h = idx & 31;
  float acc = 0.f;
  for (int d = 0; d < D; d += 4) {
    float4 qq = *(const float4*)&q[b * HD + h * D + d];
    float4 bb = *(const float4*)&bkv[h * D + d];
    acc += qq.x * bb.x + qq.y * bb.y + qq.z * bb.z + qq.w * bb.w;
  }
  qb[idx] = acc;
}

// ---------------------------------------------------------------------------
// Kernel C: attn[b,h,s] = qhat[b,h,:] . ckv[b,s,:] + qb[b,h]
// grid (16 b, 16 s-chunks of 256) x 256; qhat[b] (64 KiB) in LDS.
// Thread tile: 4 h x 8 s.
// ---------------------------------------------------------------------------
__global__ __launch_bounds__(256) void k_logits(const float* __restrict__ qhat,
                                                const float* __restrict__ qbv,
                                                const float* __restrict__ ckv,
                                                float* __restrict__ attn) {
  int b = blockIdx.x;
  int s0 = blockIdx.y * 256;
  __shared__ float qs[H * R];  // 64 KiB
  int tid = threadIdx.x;
  const float* qh = qhat + (size_t)b * H * R;
  for (int idx = tid * 4; idx < H * R; idx += 1024)
    *(float4*)&qs[idx] = *(const float4*)&qh[idx];
  __syncthreads();

  int h0 = (tid >> 5) * 4;
  int sbase = s0 + (tid & 31) * 8;
  float acc[4][8];
#pragma unroll
  for (int i = 0; i < 4; ++i)
#pragma unroll
    for (int j = 0; j < 8; ++j) acc[i][j] = 0.f;

  const float* cbase = ckv + ((size_t)(b * S + sbase)) * R;
  for (int r = 0; r < R; r += 4) {
    float4 qv[4];
#pragma unroll
    for (int i = 0; i < 4; ++i) qv[i] = *(const float4*)&qs[(h0 + i) * R + r];
#pragma unroll
    for (int j = 0; j < 8; ++j) {
      float4 c = *(const float4*)&cbase[(size_t)j * R + r];
#pragma unroll
      for (int i = 0; i < 4; ++i)
        acc[i][j] += qv[i].x * c.x + qv[i].y * c.y + qv[i].z * c.z + qv[i].w * c.w;
    }
  }
#pragma unroll
  for (int i = 0; i < 4; ++i) {
    float qb0 = qbv[b * H + h0 + i];
    float* arow = attn + ((size_t)(b * H + h0 + i)) * S + sbase;
    float4 o0 = {acc[i][0] + qb0, acc[i][1] + qb0, acc[i][2] + qb0, acc[i][3] + qb0};
    float4 o1 = {acc[i][4] + qb0, acc[i][5] + qb0, acc[i][6] + qb0, acc[i][7] + qb0};
    *(float4*)&arow[0] = o0;
    *(float4*)&arow[4] = o1;
  }
}

// ---------------------------------------------------------------------------
// Kernel D: in-place row softmax over attn (512 rows of 4096)
// ---------------------------------------------------------------------------
__global__ __launch_bounds__(256) void k_softmax(float* __restrict__ attn) {
  float* p = attn + (size_t)blockIdx.x * S;
  int tid = threadIdx.x;
  float4 v[4];
  float m = -1e30f;
#pragma unroll
  for (int i = 0; i < 4; ++i) {
    v[i] = *(const float4*)&p[tid * 4 + i * 1024];
    m = fmaxf(m, fmaxf(fmaxf(v[i].x, v[i].y), fmaxf(v[i].z, v[i].w)));
  }
#pragma unroll
  for (int off = 32; off > 0; off >>= 1) m = fmaxf(m, __shfl_xor(m, off));
  __shared__ float redm[4], reds[4];
  int lane = tid & 63, wv = tid >> 6;
  if (lane == 0) redm[wv] = m;
  __syncthreads();
  m = fmaxf(fmaxf(redm[0], redm[1]), fmaxf(redm[2], redm[3]));
  float sum = 0.f;
#pragma unroll
  for (int i = 0; i < 4; ++i) {
    v[i].x = __expf(v[i].x - m); sum += v[i].x;
    v[i].y = __expf(v[i].y - m); sum += v[i].y;
    v[i].z = __expf(v[i].z - m); sum += v[i].z;
    v[i].w = __expf(v[i].w - m); sum += v[i].w;
  }
#pragma unroll
  for (int off = 32; off > 0; off >>= 1) sum += __shfl_xor(sum, off);
  if (lane == 0) reds[wv] = sum;
  __syncthreads();
  sum = reds[0] + reds[1] + reds[2] + reds[3];
  float inv = 1.f / sum;
#pragma unroll
  for (int i = 0; i < 4; ++i) {
    v[i].x *= inv; v[i].y *= inv; v[i].z *= inv; v[i].w *= inv;
    *(float4*)&p[tid * 4 + i * 1024] = v[i];
  }
}

// ---------------------------------------------------------------------------
// Kernel E: partial ctx: part[b,sc,h,r] = sum_{s in chunk} P[b,h,s]*ckv[b,s,r]
// grid (16 b, 16 s-chunks of 256) x 512; P-chunk transposed in LDS.
// Thread tile: 4 h x 8 r; ckv rows read fully coalesced.
// ---------------------------------------------------------------------------
__global__ __launch_bounds__(512) void k_ctx(const float* __restrict__ attn,
                                             const float* __restrict__ ckv,
                                             float* __restrict__ part) {
  int b = blockIdx.x;
  int sc = blockIdx.y;
  int s0 = sc * 256;
  __shared__ float pt[256][36];  // 36 KiB, padded (stride 36 floats)
  int tid = threadIdx.x;
  for (int idx = tid; idx < H * 256; idx += 512) {
    int h = idx >> 8, sl = idx & 255;
    pt[sl][h] = attn[((size_t)(b * H + h)) * S + s0 + sl];
  }
  __syncthreads();

  int r0 = (tid & 63) * 8;
  int h0 = (tid >> 6) * 4;
  float acc[4][8];
#pragma unroll
  for (int i = 0; i < 4; ++i)
#pragma unroll
    for (int j = 0; j < 8; ++j) acc[i][j] = 0.f;

  const float* cb = ckv + ((size_t)(b * S + s0)) * R + r0;
  for (int s = 0; s < 256; ++s) {
    float4 p4 = *(const float4*)&pt[s][h0];
    const float* crow = cb + (size_t)s * R;
    float4 ca = *(const float4*)crow;
    float4 cc = *(const float4*)(crow + 4);
    float pv[4] = {p4.x, p4.y, p4.z, p4.w};
    float cv[8] = {ca.x, ca.y, ca.z, ca.w, cc.x, cc.y, cc.z, cc.w};
#pragma unroll
    for (int i = 0; i < 4; ++i)
#pragma unroll
      for (int j = 0; j < 8; ++j) acc[i][j] += pv[i] * cv[j];
  }

  float* pb = part + (((size_t)(b * 16 + sc)) * H + h0) * R + r0;
#pragma unroll
  for (int i = 0; i < 4; ++i) {
    float4 w0 = {acc[i][0], acc[i][1], acc[i][2], acc[i][3]};
    float4 w1 = {acc[i][4], acc[i][5], acc[i][6], acc[i][7]};
    *(float4*)&pb[(size_t)i * R]     = w0;
    *(float4*)&pb[(size_t)i * R + 4] = w1;
  }
}

// ---------------------------------------------------------------------------
// Kernel F1: ctx[b,h,r] = sum_{sc} part[b,sc,h,r]
// ---------------------------------------------------------------------------
__global__ __launch_bounds__(256) void k_reduce(const float* __restrict__ part,
                                                float* __restrict__ ctx) {
  int idx = (blockIdx.x * 256 + threadIdx.x) * 4;  // over B*H*R
  int b = idx >> 14;
  int hr = idx & 16383;
  float4 sum = {0.f, 0.f, 0.f, 0.f};
  for (int c = 0; c < 16; ++c) {
    float4 v = *(const float4*)&part[((size_t)(b * 16 + c)) * (H * R) + hr];
    sum.x += v.x; sum.y += v.y; sum.z += v.z; sum.w += v.w;
  }
  *(float4*)&ctx[idx] = sum;
}

// ---------------------------------------------------------------------------
// Kernel F2: out[b, h*D+d] = Wkv[h*D+d,:] . ctx[b,h,:] + bkv[h*D+d]
// grid (32 h, 4 d-chunks of 32) x 256; ctx for all b in LDS (32 KiB).
// ---------------------------------------------------------------------------
__global__ __launch_bounds__(256) void k_out(const float* __restrict__ ctx,
                                             const float* __restrict__ Wkv,
                                             const float* __restrict__ bkv,
                                             float* __restrict__ out) {
  int h = blockIdx.x;
  int d0 = blockIdx.y * 32;
  __shared__ float cs[B][R];  // 32 KiB
  int tid = threadIdx.x;
  for (int idx = tid * 4; idx < B * R; idx += 1024) {
    int b = idx >> 9, r = idx & 511;
    *(float4*)&cs[b][r] = *(const float4*)&ctx[(size_t)(b * H + h) * R + r];
  }
  __syncthreads();

  int dg = tid & 31;
  int bg = tid >> 5;  // 0..7 -> 2 batches each
  int d = d0 + dg;
  int b0 = bg * 2;
  float acc0 = 0.f, acc1 = 0.f;
  const float* wrow = Wkv + ((size_t)(h * D + d)) * R;
  for (int i = 0; i < R; i += 4) {
    float4 w4 = *(const float4*)&wrow[i];
    float4 ca = *(const float4*)&cs[b0][i];
    float4 cb = *(const float4*)&cs[b0 + 1][i];
    acc0 += w4.x * ca.x + w4.y * ca.y + w4.z * ca.z + w4.w * ca.w;
    acc1 += w4.x * cb.x + w4.y * cb.y + w4.z * cb.z + w4.w * cb.w;
  }
  float bv = bkv[h * D + d];
  out[(size_t)b0 * HD + h * D + d]       = acc0 + bv;
  out[(size_t)(b0 + 1) * HD + h * D + d] = acc1 + bv;
}

// ---------------------------------------------------------------------------
extern "C" void kernel_launch(void* const* d_in, const int* in_sizes, int n_in,
                              void* d_out, int out_size, void* d_ws, size_t ws_size,
                              hipStream_t stream) {
  (void)in_sizes; (void)n_in; (void)out_size; (void)ws_size;
  const float* hsq = (const float*)d_in[0];
  const float* ckv = (const float*)d_in[1];
  const float* Wq  = (const float*)d_in[2];
  const float* bq  = (const float*)d_in[3];
  const float* Wkv = (const float*)d_in[4];
  const float* bkv = (const float*)d_in[5];
  float* out = (float*)d_out;

  float* ws   = (float*)d_ws;
  float* q    = ws;                       // 65536
  float* qhat = q + 65536;                // 262144
  float* qb   = qhat + 262144;            // 512
  float* attn = qb + 512;                 // 2097152
  float* part = attn + 2097152;           // 16*B*H*R = 4194304
  float* ctx  = part + 4194304;           // 262144   (total ~27.5 MB)

  k_q<<<256, 512, 0, stream>>>(hsq, Wq, bq, q);
  k_qhat<<<dim3(32, 8), 256, 0, stream>>>(q, Wkv, qhat);
  k_qb<<<2, 256, 0, stream>>>(q, bkv, qb);
  k_logits<<<dim3(16, 16), 256, 0, stream>>>(qhat, qb, ckv, attn);
  k_softmax<<<512, 256, 0, stream>>>(attn);
  k_ctx<<<dim3(16, 16), 512, 0, stream>>>(attn, ckv, part);
  k_reduce<<<256, 256, 0, stream>>>(part, ctx);
  k_out<<<dim3(32, 4), 256, 0, stream>>>(ctx, Wkv, bkv, out);
}

// Round 4
// 142.891 us; speedup vs baseline: 1.6765x; 1.6765x over previous
//
#include <hip/hip_runtime.h>

#define B  16
#define S  4096
#define R  512          // LORA_RANK
#define QR 1536         // Q_LORA_RANK
#define H  32
#define D  128
#define HD 4096         // H*D

// ---------------------------------------------------------------------------
// Kernel A: q[b,o] = hsq[b,:] . Wq[o,:] + bq[o]
// ---------------------------------------------------------------------------
__global__ __launch_bounds__(512) void k_q(const float* __restrict__ hsq,
                                           const float* __restrict__ Wq,
                                           const float* __restrict__ bq,
                                           float* __restrict__ q) {
  __shared__ float hs[B * QR];  // 96 KiB
  int tid = threadIdx.x;
  for (int idx = tid * 4; idx < B * QR; idx += 2048)
    *(float4*)&hs[idx] = *(const float4*)&hsq[idx];
  __syncthreads();

  int wave = tid >> 6, lane = tid & 63;
  int o = blockIdx.x * 16 + wave * 2;

  float acc0[B], acc1[B];
#pragma unroll
  for (int b = 0; b < B; ++b) { acc0[b] = 0.f; acc1[b] = 0.f; }

  const float* w0r = Wq + (size_t)o * QR;
  const float* w1r = w0r + QR;
  for (int k = lane * 4; k < QR; k += 256) {
    float4 wa = *(const float4*)&w0r[k];
    float4 wb = *(const float4*)&w1r[k];
#pragma unroll
    for (int b = 0; b < B; ++b) {
      float4 h4 = *(const float4*)&hs[b * QR + k];
      acc0[b] += wa.x * h4.x + wa.y * h4.y + wa.z * h4.z + wa.w * h4.w;
      acc1[b] += wb.x * h4.x + wb.y * h4.y + wb.z * h4.z + wb.w * h4.w;
    }
  }
#pragma unroll
  for (int b = 0; b < B; ++b) {
    float v0 = acc0[b], v1 = acc1[b];
#pragma unroll
    for (int off = 32; off > 0; off >>= 1) {
      v0 += __shfl_xor(v0, off);
      v1 += __shfl_xor(v1, off);
    }
    if (lane == 0) {
      q[b * HD + o]     = v0 + bq[o];
      q[b * HD + o + 1] = v1 + bq[o + 1];
    }
  }
}

// ---------------------------------------------------------------------------
// Kernel B: qhat[b,h,r] = sum_d q[b, h*D+d] * Wkv[h*D+d, r]
// ---------------------------------------------------------------------------
__global__ __launch_bounds__(256) void k_qhat(const float* __restrict__ q,
                                              const float* __restrict__ Wkv,
                                              float* __restrict__ qhat) {
  int h = blockIdx.x;
  int r0 = blockIdx.y * 64;
  __shared__ float qs[B][D];
  int tid = threadIdx.x;
  for (int idx = tid; idx < B * D; idx += 256) {
    int b = idx >> 7, d = idx & (D - 1);
    qs[b][d] = q[b * HD + h * D + d];
  }
  __syncthreads();

  int r_l = tid & 63, bg = tid >> 6;
  float acc[4] = {0.f, 0.f, 0.f, 0.f};
  const float* wbase = Wkv + (size_t)(h * D) * R + r0 + r_l;
  for (int d = 0; d < D; d += 4) {
    float w0 = wbase[(d + 0) * R];
    float w1 = wbase[(d + 1) * R];
    float w2 = wbase[(d + 2) * R];
    float w3 = wbase[(d + 3) * R];
#pragma unroll
    for (int i = 0; i < 4; ++i) {
      float4 q4 = *(const float4*)&qs[bg * 4 + i][d];
      acc[i] += q4.x * w0 + q4.y * w1 + q4.z * w2 + q4.w * w3;
    }
  }
#pragma unroll
  for (int i = 0; i < 4; ++i)
    qhat[((size_t)(bg * 4 + i) * H + h) * R + r0 + r_l] = acc[i];
}

// ---------------------------------------------------------------------------
// Kernel qb: qb[b,h] = sum_d q[b,h,d] * bkv[h*D+d]
// ---------------------------------------------------------------------------
__global__ __launch_bounds__(256) void k_qb(const float* __restrict__ q,
                                            const float* __restrict__ bkv,
                                            float* __restrict__ qb) {
  int idx = blockIdx.x * 256 + threadIdx.x;  // 0..511
  int b = idx >> 5, h = idx & 31;
  float acc = 0.f;
  for (int d = 0; d < D; d += 4) {
    float4 qq = *(const float4*)&q[b * HD + h * D + d];
    float4 bb = *(const float4*)&bkv[h * D + d];
    acc += qq.x * bb.x + qq.y * bb.y + qq.z * bb.z + qq.w * bb.w;
  }
  qb[idx] = acc;
}

// ---------------------------------------------------------------------------
// Fused flash kernel: per (b, s-chunk of SC rows):
//   phase 1: logits L[32][SC] = qhat . ckv^T (k-tiled through LDS)
//   local softmax (m, l per h) in LDS
//   phase 2: partial ctx[32][512] = P . ckv (same LDS staging), + m/l out
// grid (B, S/SC) x 256 threads.
// ---------------------------------------------------------------------------
template <int SC>
__global__ __launch_bounds__(256) void k_fused(const float* __restrict__ qhat,
                                               const float* __restrict__ qbv,
                                               const float* __restrict__ ckv,
                                               float* __restrict__ part,
                                               float* __restrict__ mbuf,
                                               float* __restrict__ lbuf) {
  constexpr int CH = S / SC;
  constexpr int KT = 64;
  constexpr int NJ = SC / 32;
  __shared__ float qs[H][KT + 4];     // 8.7 KiB
  __shared__ float cs[SC][KT + 4];    // SC=128: 34.8 KiB
  __shared__ float Ls[H][SC + 4];     // SC=128: 16.9 KiB

  const int b = blockIdx.x;
  const int chunk = blockIdx.y;
  const int s0 = chunk * SC;
  const int tid = threadIdx.x;
  const int lane = tid & 31;
  const int hg4 = (tid >> 5) * 4;
  const int srow = tid >> 4;
  const int c4 = (tid & 15) * 4;

  const float* qbase = qhat + (size_t)b * H * R;
  const float* cbase = ckv + ((size_t)b * S + s0) * R;

  float acc[4][NJ];
#pragma unroll
  for (int i = 0; i < 4; ++i)
#pragma unroll
    for (int j = 0; j < NJ; ++j) acc[i][j] = 0.f;

  // ---- phase 1: QK^T over k-tiles ----
  for (int kt = 0; kt < R; kt += KT) {
    *(float4*)&qs[srow][c4]      = *(const float4*)&qbase[(size_t)srow * R + kt + c4];
    *(float4*)&qs[srow + 16][c4] = *(const float4*)&qbase[(size_t)(srow + 16) * R + kt + c4];
#pragma unroll
    for (int p = 0; p < SC / 16; ++p)
      *(float4*)&cs[srow + 16 * p][c4] =
          *(const float4*)&cbase[(size_t)(srow + 16 * p) * R + kt + c4];
    __syncthreads();
#pragma unroll 4
    for (int r4 = 0; r4 < KT; r4 += 4) {
      float4 qv[4], cv[NJ];
#pragma unroll
      for (int i = 0; i < 4; ++i) qv[i] = *(const float4*)&qs[hg4 + i][r4];
#pragma unroll
      for (int j = 0; j < NJ; ++j) cv[j] = *(const float4*)&cs[lane + 32 * j][r4];
#pragma unroll
      for (int i = 0; i < 4; ++i)
#pragma unroll
        for (int j = 0; j < NJ; ++j)
          acc[i][j] += qv[i].x * cv[j].x + qv[i].y * cv[j].y +
                       qv[i].z * cv[j].z + qv[i].w * cv[j].w;
    }
    __syncthreads();
  }

#pragma unroll
  for (int i = 0; i < 4; ++i) {
    float bias = qbv[b * H + hg4 + i];
#pragma unroll
    for (int j = 0; j < NJ; ++j) Ls[hg4 + i][lane + 32 * j] = acc[i][j] + bias;
  }
  __syncthreads();

  // ---- local softmax: 8 threads per h ----
  {
    const int h = tid >> 3, sl = tid & 7;
    float vals[SC / 8];
    float m = -3.0e38f;
#pragma unroll
    for (int k = 0; k < SC / 8; ++k) {
      vals[k] = Ls[h][sl + 8 * k];
      m = fmaxf(m, vals[k]);
    }
    m = fmaxf(m, __shfl_xor(m, 1));
    m = fmaxf(m, __shfl_xor(m, 2));
    m = fmaxf(m, __shfl_xor(m, 4));
    float sum = 0.f;
#pragma unroll
    for (int k = 0; k < SC / 8; ++k) {
      float e = __expf(vals[k] - m);
      Ls[h][sl + 8 * k] = e;
      sum += e;
    }
    sum += __shfl_xor(sum, 1);
    sum += __shfl_xor(sum, 2);
    sum += __shfl_xor(sum, 4);
    if (sl == 0) {
      mbuf[((size_t)b * CH + chunk) * H + h] = m;
      lbuf[((size_t)b * CH + chunk) * H + h] = sum;
    }
  }
  __syncthreads();

  // ---- phase 2: partial ctx = P . ckv ----
  const int h2 = (tid >> 4) * 2;
  const int r4b = (tid & 15) * 4;
  for (int kt = 0; kt < R; kt += KT) {
#pragma unroll
    for (int p = 0; p < SC / 16; ++p)
      *(float4*)&cs[srow + 16 * p][c4] =
          *(const float4*)&cbase[(size_t)(srow + 16 * p) * R + kt + c4];
    __syncthreads();
    float4 a0 = {0.f, 0.f, 0.f, 0.f}, a1 = {0.f, 0.f, 0.f, 0.f};
#pragma unroll 4
    for (int s = 0; s < SC; ++s) {
      float p0 = Ls[h2][s], p1 = Ls[h2 + 1][s];
      float4 c = *(const float4*)&cs[s][r4b];
      a0.x += p0 * c.x; a0.y += p0 * c.y; a0.z += p0 * c.z; a0.w += p0 * c.w;
      a1.x += p1 * c.x; a1.y += p1 * c.y; a1.z += p1 * c.z; a1.w += p1 * c.w;
    }
    float* pb = part + (((size_t)b * CH + chunk) * H + h2) * R + kt + r4b;
    *(float4*)pb = a0;
    *(float4*)(pb + R) = a1;
    __syncthreads();
  }
}

// ---------------------------------------------------------------------------
// Combine: ctx[b,h,r] = sum_c e^{m_c-M} part[b,c,h,r] / sum_c e^{m_c-M} l_c
// grid B*H x 256
// ---------------------------------------------------------------------------
template <int CH>
__global__ __launch_bounds__(256) void k_combine(const float* __restrict__ part,
                                                 const float* __restrict__ mbuf,
                                                 const float* __restrict__ lbuf,
                                                 float* __restrict__ ctx) {
  const int bid = blockIdx.x;
  const int b = bid >> 5, h = bid & 31;
  const int tid = threadIdx.x;
  float mv[CH], w[CH];
  float M = -3.0e38f;
#pragma unroll
  for (int c = 0; c < CH; ++c) {
    mv[c] = mbuf[((size_t)b * CH + c) * H + h];
    M = fmaxf(M, mv[c]);
  }
  float denom = 0.f;
#pragma unroll
  for (int c = 0; c < CH; ++c) {
    w[c] = __expf(mv[c] - M);
    denom += w[c] * lbuf[((size_t)b * CH + c) * H + h];
  }
  const float inv = 1.f / denom;
  float s0 = 0.f, s1 = 0.f;
#pragma unroll
  for (int c = 0; c < CH; ++c) {
    const float* pp = part + (((size_t)b * CH + c) * H + h) * R;
    s0 += w[c] * pp[tid];
    s1 += w[c] * pp[tid + 256];
  }
  ctx[((size_t)b * H + h) * R + tid] = s0 * inv;
  ctx[((size_t)b * H + h) * R + tid + 256] = s1 * inv;
}

// ---------------------------------------------------------------------------
// Kernel F2: out[b, h*D+d] = Wkv[h*D+d,:] . ctx[b,h,:] + bkv[h*D+d]
// ---------------------------------------------------------------------------
__global__ __launch_bounds__(256) void k_out(const float* __restrict__ ctx,
                                             const float* __restrict__ Wkv,
                                             const float* __restrict__ bkv,
                                             float* __restrict__ out) {
  int h = blockIdx.x;
  int d0 = blockIdx.y * 32;
  __shared__ float cs[B][R];  // 32 KiB
  int tid = threadIdx.x;
  for (int idx = tid * 4; idx < B * R; idx += 1024) {
    int b = idx >> 9, r = idx & 511;
    *(float4*)&cs[b][r] = *(const float4*)&ctx[(size_t)(b * H + h) * R + r];
  }
  __syncthreads();

  int dg = tid & 31;
  int bg = tid >> 5;
  int d = d0 + dg;
  int b0 = bg * 2;
  float acc0 = 0.f, acc1 = 0.f;
  const float* wrow = Wkv + ((size_t)(h * D + d)) * R;
  for (int i = 0; i < R; i += 4) {
    float4 w4 = *(const float4*)&wrow[i];
    float4 ca = *(const float4*)&cs[b0][i];
    float4 cb = *(const float4*)&cs[b0 + 1][i];
    acc0 += w4.x * ca.x + w4.y * ca.y + w4.z * ca.z + w4.w * ca.w;
    acc1 += w4.x * cb.x + w4.y * cb.y + w4.z * cb.z + w4.w * cb.w;
  }
  float bv = bkv[h * D + d];
  out[(size_t)b0 * HD + h * D + d]       = acc0 + bv;
  out[(size_t)(b0 + 1) * HD + h * D + d] = acc1 + bv;
}

// ---------------------------------------------------------------------------
extern "C" void kernel_launch(void* const* d_in, const int* in_sizes, int n_in,
                              void* d_out, int out_size, void* d_ws, size_t ws_size,
                              hipStream_t stream) {
  (void)in_sizes; (void)n_in; (void)out_size;
  const float* hsq = (const float*)d_in[0];
  const float* ckv = (const float*)d_in[1];
  const float* Wq  = (const float*)d_in[2];
  const float* bq  = (const float*)d_in[3];
  const float* Wkv = (const float*)d_in[4];
  const float* bkv = (const float*)d_in[5];
  float* out = (float*)d_out;

  float* ws   = (float*)d_ws;
  float* q    = ws;                 // 65536
  float* qhat = q + 65536;          // 262144
  float* qb   = qhat + 262144;      // 512
  float* ctx  = qb + 512;           // 262144

  // choose chunking by available workspace
  const size_t base_f = 65536 + 262144 + 512 + 262144;
  const size_t need32 = (base_f + 2 * (size_t)B * 32 * H + (size_t)B * 32 * H * R) * 4;

  k_q<<<256, 512, 0, stream>>>(hsq, Wq, bq, q);
  k_qhat<<<dim3(32, 8), 256, 0, stream>>>(q, Wkv, qhat);
  k_qb<<<2, 256, 0, stream>>>(q, bkv, qb);

  if (ws_size >= need32) {
    constexpr int CH = 32;  // SC = 128
    float* mbuf = ctx + 262144;
    float* lbuf = mbuf + (size_t)B * CH * H;
    float* part = lbuf + (size_t)B * CH * H;
    k_fused<128><<<dim3(B, CH), 256, 0, stream>>>(qhat, qb, ckv, part, mbuf, lbuf);
    k_combine<CH><<<B * H, 256, 0, stream>>>(part, mbuf, lbuf, ctx);
  } else {
    constexpr int CH = 16;  // SC = 256
    float* mbuf = ctx + 262144;
    float* lbuf = mbuf + (size_t)B * CH * H;
    float* part = lbuf + (size_t)B * CH * H;
    k_fused<256><<<dim3(B, CH), 256, 0, stream>>>(qhat, qb, ckv, part, mbuf, lbuf);
    k_combine<CH><<<B * H, 256, 0, stream>>>(part, mbuf, lbuf, ctx);
  }

  k_out<<<dim3(32, 4), 256, 0, stream>>>(ctx, Wkv, bkv, out);
}

// Round 5
// 106.314 us; speedup vs baseline: 2.2533x; 1.3441x over previous
//
#include <hip/hip_runtime.h>

#define B  16
#define S  4096
#define R  512          // LORA_RANK
#define QR 1536         // Q_LORA_RANK
#define H  32
#define D  128
#define HD 4096         // H*D
#define SC 128          // s-chunk per block
#define CH 32           // S/SC

using f32x4 = __attribute__((ext_vector_type(4))) float;
using s16x8 = __attribute__((ext_vector_type(8))) short;

__device__ __forceinline__ ushort bf_hi(float x) {
  return (ushort)(__float_as_uint(x) >> 16);        // truncation
}
__device__ __forceinline__ float bf_res(float x) {  // exact residual of truncation
  return x - __uint_as_float(__float_as_uint(x) & 0xFFFF0000u);
}
__device__ __forceinline__ ushort f2bf_rne(float x) {
  uint u = __float_as_uint(x);
  return (ushort)((u + 0x7FFFu + ((u >> 16) & 1u)) >> 16);
}

// ---------------------------------------------------------------------------
// Kernel A: q[b,o] = hsq[b,:] . Wq[o,:] + bq[o]
// ---------------------------------------------------------------------------
__global__ __launch_bounds__(512) void k_q(const float* __restrict__ hsq,
                                           const float* __restrict__ Wq,
                                           const float* __restrict__ bq,
                                           float* __restrict__ q) {
  __shared__ float hs[B * QR];  // 96 KiB
  int tid = threadIdx.x;
  for (int idx = tid * 4; idx < B * QR; idx += 2048)
    *(float4*)&hs[idx] = *(const float4*)&hsq[idx];
  __syncthreads();

  int wave = tid >> 6, lane = tid & 63;
  int o = blockIdx.x * 16 + wave * 2;

  float acc0[B], acc1[B];
#pragma unroll
  for (int b = 0; b < B; ++b) { acc0[b] = 0.f; acc1[b] = 0.f; }

  const float* w0r = Wq + (size_t)o * QR;
  const float* w1r = w0r + QR;
  for (int k = lane * 4; k < QR; k += 256) {
    float4 wa = *(const float4*)&w0r[k];
    float4 wb = *(const float4*)&w1r[k];
#pragma unroll
    for (int b = 0; b < B; ++b) {
      float4 h4 = *(const float4*)&hs[b * QR + k];
      acc0[b] += wa.x * h4.x + wa.y * h4.y + wa.z * h4.z + wa.w * h4.w;
      acc1[b] += wb.x * h4.x + wb.y * h4.y + wb.z * h4.z + wb.w * h4.w;
    }
  }
#pragma unroll
  for (int b = 0; b < B; ++b) {
    float v0 = acc0[b], v1 = acc1[b];
#pragma unroll
    for (int off = 32; off > 0; off >>= 1) {
      v0 += __shfl_xor(v0, off);
      v1 += __shfl_xor(v1, off);
    }
    if (lane == 0) {
      q[b * HD + o]     = v0 + bq[o];
      q[b * HD + o + 1] = v1 + bq[o + 1];
    }
  }
}

// ---------------------------------------------------------------------------
// Kernel B: qhat[b,h,r] = sum_d q[b, h*D+d] * Wkv[h*D+d, r]
// ---------------------------------------------------------------------------
__global__ __launch_bounds__(256) void k_qhat(const float* __restrict__ q,
                                              const float* __restrict__ Wkv,
                                              float* __restrict__ qhat) {
  int h = blockIdx.x;
  int r0 = blockIdx.y * 64;
  __shared__ float qs[B][D];
  int tid = threadIdx.x;
  for (int idx = tid; idx < B * D; idx += 256) {
    int b = idx >> 7, d = idx & (D - 1);
    qs[b][d] = q[b * HD + h * D + d];
  }
  __syncthreads();

  int r_l = tid & 63, bg = tid >> 6;
  float acc[4] = {0.f, 0.f, 0.f, 0.f};
  const float* wbase = Wkv + (size_t)(h * D) * R + r0 + r_l;
  for (int d = 0; d < D; d += 4) {
    float w0 = wbase[(d + 0) * R];
    float w1 = wbase[(d + 1) * R];
    float w2 = wbase[(d + 2) * R];
    float w3 = wbase[(d + 3) * R];
#pragma unroll
    for (int i = 0; i < 4; ++i) {
      float4 q4 = *(const float4*)&qs[bg * 4 + i][d];
      acc[i] += q4.x * w0 + q4.y * w1 + q4.z * w2 + q4.w * w3;
    }
  }
#pragma unroll
  for (int i = 0; i < 4; ++i)
    qhat[((size_t)(bg * 4 + i) * H + h) * R + r0 + r_l] = acc[i];
}

// ---------------------------------------------------------------------------
// Fused MFMA flash kernel. grid (B, CH) x 256 (4 waves).
// Phase 1: logits[32][128] = qhat . ckv^T, split-bf16 (3 MFMAs) for fp32-grade
//          accuracy. A-frags straight from global (L2-hot); ckv k-tiled in LDS
//          bf16 hi/lo with XOR-chunk swizzle.
// softmax: per-h over the 128-chunk; unnormalized P -> LDS bf16 (swizzled).
// Phase 2: part[32 h][512 r] = P . ckv, plain bf16. ckv restaged transposed
//          [64 r][128 s] per r-tile (global re-read is L2/L3-hot).
// Note: the q.bkv logit term is constant per (b,h) row -> cancels in softmax.
// ---------------------------------------------------------------------------
__global__ __launch_bounds__(256) void k_fmha(const float* __restrict__ qhat,
                                              const float* __restrict__ ckv,
                                              float* __restrict__ part,
                                              float* __restrict__ mbuf,
                                              float* __restrict__ lbuf) {
  // element (s,k): idx = s*64 + ((k>>3)^(s&7))*8 + (k&7)
  __shared__ __align__(16) ushort cs1h[SC * 64];  // 16 KiB
  __shared__ __align__(16) ushort cs1l[SC * 64];  // 16 KiB
  __shared__ __align__(16) float  Ls[H * 132];    // 16.9 KiB
  // element (h,s): idx = h*128 + ((s>>3)^(h&7))*8 + (s&7)
  __shared__ __align__(16) ushort Ps[H * 128];    // 8 KiB
  // element (r,s): idx = r*128 + ((s>>3)^(r&7))*8 + (s&7)
  __shared__ __align__(16) ushort cs2[64 * SC];   // 16 KiB

  const int b = blockIdx.x, chunk = blockIdx.y;
  const int tid = threadIdx.x;
  const int lane = tid & 63, w = tid >> 6;
  const float* cbase = ckv + ((size_t)b * S + (size_t)chunk * SC) * R;
  const float* qbase = qhat + (size_t)b * H * R;

  f32x4 acc[2][2];
#pragma unroll
  for (int i = 0; i < 2; ++i)
#pragma unroll
    for (int j = 0; j < 2; ++j) acc[i][j] = {0.f, 0.f, 0.f, 0.f};

  const int st_s = tid >> 1;
  const int st_kh = (tid & 1) * 32;

  // ---------------- phase 1: QK^T ----------------
  for (int kt = 0; kt < R; kt += 64) {
    {
      const float* src = cbase + (size_t)st_s * R + kt + st_kh;
#pragma unroll
      for (int j = 0; j < 8; ++j) {
        float4 v = *(const float4*)(src + 4 * j);
        int k0 = st_kh + 4 * j;
        int idx = st_s * 64 + (((k0 >> 3) ^ (st_s & 7)) << 3) + (k0 & 7);
        *(uint*)&cs1h[idx]     = (uint)bf_hi(v.x) | ((uint)bf_hi(v.y) << 16);
        *(uint*)&cs1h[idx + 2] = (uint)bf_hi(v.z) | ((uint)bf_hi(v.w) << 16);
        *(uint*)&cs1l[idx]     = (uint)bf_hi(bf_res(v.x)) | ((uint)bf_hi(bf_res(v.y)) << 16);
        *(uint*)&cs1l[idx + 2] = (uint)bf_hi(bf_res(v.z)) | ((uint)bf_hi(bf_res(v.w)) << 16);
      }
    }
    __syncthreads();
#pragma unroll
    for (int ks = 0; ks < 2; ++ks) {
      const int kk = kt + ks * 32 + (lane >> 4) * 8;
      s16x8 ah[2], al[2], bh[2], bl[2];
#pragma unroll
      for (int mt = 0; mt < 2; ++mt) {
        const float* qp = qbase + (size_t)((lane & 15) + 16 * mt) * R + kk;
        float4 q0 = *(const float4*)qp;
        float4 q1 = *(const float4*)(qp + 4);
        float qv[8] = {q0.x, q0.y, q0.z, q0.w, q1.x, q1.y, q1.z, q1.w};
        s16x8 th, tl;
#pragma unroll
        for (int e = 0; e < 8; ++e) {
          th[e] = (short)bf_hi(qv[e]);
          tl[e] = (short)bf_hi(bf_res(qv[e]));
        }
        ah[mt] = th; al[mt] = tl;
      }
#pragma unroll
      for (int ntl = 0; ntl < 2; ++ntl) {
        int sf = (lane & 15) + 32 * w + 16 * ntl;
        int kb = ks * 4 + (lane >> 4);
        int idx = sf * 64 + ((kb ^ (sf & 7)) << 3);
        bh[ntl] = *(s16x8*)&cs1h[idx];
        bl[ntl] = *(s16x8*)&cs1l[idx];
      }
#pragma unroll
      for (int mt = 0; mt < 2; ++mt)
#pragma unroll
        for (int ntl = 0; ntl < 2; ++ntl) {
          acc[mt][ntl] = __builtin_amdgcn_mfma_f32_16x16x32_bf16(ah[mt], bh[ntl], acc[mt][ntl], 0, 0, 0);
          acc[mt][ntl] = __builtin_amdgcn_mfma_f32_16x16x32_bf16(ah[mt], bl[ntl], acc[mt][ntl], 0, 0, 0);
          acc[mt][ntl] = __builtin_amdgcn_mfma_f32_16x16x32_bf16(al[mt], bh[ntl], acc[mt][ntl], 0, 0, 0);
        }
    }
    __syncthreads();
  }

  // logits -> Ls  (D layout: col=lane&15, row=(lane>>4)*4+reg)
#pragma unroll
  for (int mt = 0; mt < 2; ++mt)
#pragma unroll
    for (int ntl = 0; ntl < 2; ++ntl)
#pragma unroll
      for (int i = 0; i < 4; ++i) {
        int row = 16 * mt + (lane >> 4) * 4 + i;
        int col = 32 * w + 16 * ntl + (lane & 15);
        Ls[row * 132 + col] = acc[mt][ntl][i];
      }
  __syncthreads();

  // ---------------- softmax (8 threads per h) ----------------
  {
    const int h = tid >> 3, sl = tid & 7;
    float vals[16];
    float m = -3.0e38f;
#pragma unroll
    for (int k = 0; k < 16; ++k) {
      vals[k] = Ls[h * 132 + sl + 8 * k];
      m = fmaxf(m, vals[k]);
    }
    m = fmaxf(m, __shfl_xor(m, 1));
    m = fmaxf(m, __shfl_xor(m, 2));
    m = fmaxf(m, __shfl_xor(m, 4));
    float sum = 0.f;
#pragma unroll
    for (int k = 0; k < 16; ++k) {
      float e = __expf(vals[k] - m);
      sum += e;
      Ps[h * 128 + ((k ^ (h & 7)) << 3) + sl] = f2bf_rne(e);
    }
    sum += __shfl_xor(sum, 1);
    sum += __shfl_xor(sum, 2);
    sum += __shfl_xor(sum, 4);
    if (sl == 0) {
      mbuf[((size_t)b * CH + chunk) * H + h] = m;
      lbuf[((size_t)b * CH + chunk) * H + h] = sum;
    }
  }
  __syncthreads();

  // ---------------- phase 2: part = P . ckv ----------------
  // Hoist P fragments (rt-invariant): B[k=s][n=h]
  s16x8 bp[4][2];
#pragma unroll
  for (int kt = 0; kt < 4; ++kt)
#pragma unroll
    for (int nt = 0; nt < 2; ++nt) {
      int h = 16 * nt + (lane & 15);
      int kb = kt * 4 + (lane >> 4);
      bp[kt][nt] = *(s16x8*)&Ps[h * 128 + ((kb ^ (h & 7)) << 3)];
    }

  float* pb = part + (size_t)(b * CH + chunk) * H * R;
  const int b7 = tid & 7, sp = tid >> 3;

  for (int rt = 0; rt < 8; ++rt) {
    const int r0 = rt * 64;
    // stage cs2[r][s] transposed, bf16-hi
#pragma unroll
    for (int so = 0; so < 2; ++so) {
      int s = 2 * sp + 64 * so;
      const float* row0 = cbase + (size_t)s * R + r0;
      const float* row1 = row0 + R;
#pragma unroll
      for (int i = 0; i < 8; ++i) {
        int r = b7 + 8 * i;
        int idx = r * 128 + (((s >> 3) ^ (r & 7)) << 3) + (s & 7);
        *(uint*)&cs2[idx] = (uint)f2bf_rne(row0[r]) | ((uint)f2bf_rne(row1[r]) << 16);
      }
    }
    __syncthreads();

    f32x4 acc2[2];
    acc2[0] = {0.f, 0.f, 0.f, 0.f};
    acc2[1] = {0.f, 0.f, 0.f, 0.f};
    const int rl = 16 * w + (lane & 15);
#pragma unroll
    for (int kt = 0; kt < 4; ++kt) {
      int kb = kt * 4 + (lane >> 4);
      s16x8 a2 = *(s16x8*)&cs2[rl * 128 + ((kb ^ (rl & 7)) << 3)];
#pragma unroll
      for (int nt = 0; nt < 2; ++nt)
        acc2[nt] = __builtin_amdgcn_mfma_f32_16x16x32_bf16(a2, bp[kt][nt], acc2[nt], 0, 0, 0);
    }
#pragma unroll
    for (int nt = 0; nt < 2; ++nt) {
      int h = 16 * nt + (lane & 15);
#pragma unroll
      for (int i = 0; i < 4; ++i) {
        int rg = r0 + 16 * w + (lane >> 4) * 4 + i;
        pb[(size_t)h * R + rg] = acc2[nt][i];
      }
    }
    __syncthreads();
  }
}

// ---------------------------------------------------------------------------
// Combine: ctx[b,h,r] = sum_c e^{m_c-M} part[b,c,h,r] / sum_c e^{m_c-M} l_c
// ---------------------------------------------------------------------------
__global__ __launch_bounds__(256) void k_combine(const float* __restrict__ part,
                                                 const float* __restrict__ mbuf,
                                                 const float* __restrict__ lbuf,
                                                 float* __restrict__ ctx) {
  const int bid = blockIdx.x;
  const int b = bid >> 5, h = bid & 31;
  const int tid = threadIdx.x;
  float mv[CH], wv[CH];
  float M = -3.0e38f;
#pragma unroll
  for (int c = 0; c < CH; ++c) {
    mv[c] = mbuf[((size_t)b * CH + c) * H + h];
    M = fmaxf(M, mv[c]);
  }
  float denom = 0.f;
#pragma unroll
  for (int c = 0; c < CH; ++c) {
    wv[c] = __expf(mv[c] - M);
    denom += wv[c] * lbuf[((size_t)b * CH + c) * H + h];
  }
  const float inv = 1.f / denom;
  float s0 = 0.f, s1 = 0.f;
#pragma unroll
  for (int c = 0; c < CH; ++c) {
    const float* pp = part + (((size_t)b * CH + c) * H + h) * R;
    s0 += wv[c] * pp[tid];
    s1 += wv[c] * pp[tid + 256];
  }
  ctx[((size_t)b * H + h) * R + tid] = s0 * inv;
  ctx[((size_t)b * H + h) * R + tid + 256] = s1 * inv;
}

// ---------------------------------------------------------------------------
// Kernel F2: out[b, h*D+d] = Wkv[h*D+d,:] . ctx[b,h,:] + bkv[h*D+d]
// ---------------------------------------------------------------------------
__global__ __launch_bounds__(256) void k_out(const float* __restrict__ ctx,
                                             const float* __restrict__ Wkv,
                                             const float* __restrict__ bkv,
                                             float* __restrict__ out) {
  int h = blockIdx.x;
  int d0 = blockIdx.y * 32;
  __shared__ float cs[B][R];  // 32 KiB
  int tid = threadIdx.x;
  for (int idx = tid * 4; idx < B * R; idx += 1024) {
    int b = idx >> 9, r = idx & 511;
    *(float4*)&cs[b][r] = *(const float4*)&ctx[(size_t)(b * H + h) * R + r];
  }
  __syncthreads();

  int dg = tid & 31;
  int bg = tid >> 5;
  int d = d0 + dg;
  int b0 = bg * 2;
  float acc0 = 0.f, acc1 = 0.f;
  const float* wrow = Wkv + ((size_t)(h * D + d)) * R;
  for (int i = 0; i < R; i += 4) {
    float4 w4 = *(const float4*)&wrow[i];
    float4 ca = *(const float4*)&cs[b0][i];
    float4 cb = *(const float4*)&cs[b0 + 1][i];
    acc0 += w4.x * ca.x + w4.y * ca.y + w4.z * ca.z + w4.w * ca.w;
    acc1 += w4.x * cb.x + w4.y * cb.y + w4.z * cb.z + w4.w * cb.w;
  }
  float bv = bkv[h * D + d];
  out[(size_t)b0 * HD + h * D + d]       = acc0 + bv;
  out[(size_t)(b0 + 1) * HD + h * D + d] = acc1 + bv;
}

// ---------------------------------------------------------------------------
extern "C" void kernel_launch(void* const* d_in, const int* in_sizes, int n_in,
                              void* d_out, int out_size, void* d_ws, size_t ws_size,
                              hipStream_t stream) {
  (void)in_sizes; (void)n_in; (void)out_size; (void)ws_size;
  const float* hsq = (const float*)d_in[0];
  const float* ckv = (const float*)d_in[1];
  const float* Wq  = (const float*)d_in[2];
  const float* bq  = (const float*)d_in[3];
  const float* Wkv = (const float*)d_in[4];
  const float* bkv = (const float*)d_in[5];
  float* out = (float*)d_out;

  float* ws   = (float*)d_ws;
  float* q    = ws;                          // 65536
  float* qhat = q + 65536;                   // 262144
  float* ctx  = qhat + 262144;               // 262144
  float* mbuf = ctx + 262144;                // 16384
  float* lbuf = mbuf + (size_t)B * CH * H;   // 16384
  float* part = lbuf + (size_t)B * CH * H;   // 8388608  (total ~36.0 MB)

  k_q<<<256, 512, 0, stream>>>(hsq, Wq, bq, q);
  k_qhat<<<dim3(32, 8), 256, 0, stream>>>(q, Wkv, qhat);
  k_fmha<<<dim3(B, CH), 256, 0, stream>>>(qhat, ckv, part, mbuf, lbuf);
  k_combine<<<B * H, 256, 0, stream>>>(part, mbuf, lbuf, ctx);
  k_out<<<dim3(32, 4), 256, 0, stream>>>(ctx, Wkv, bkv, out);
}

// Round 6
// 90.728 us; speedup vs baseline: 2.6404x; 1.1718x over previous
//
#include <hip/hip_runtime.h>

#define B  16
#define S  4096
#define R  512          // LORA_RANK
#define QR 1536        // Q_LORA_RANK
#define H  32
#define D  128
#define HD 4096        // H*D
#define SC 128         // s-chunk per block
#define CH 32          // S/SC

using f32x4 = __attribute__((ext_vector_type(4))) float;
using s16x8 = __attribute__((ext_vector_type(8))) short;

__device__ __forceinline__ ushort bf_hi(float x) {
  return (ushort)(__float_as_uint(x) >> 16);        // truncation
}
__device__ __forceinline__ float bf_res(float x) {  // exact residual of truncation
  return x - __uint_as_float(__float_as_uint(x) & 0xFFFF0000u);
}
__device__ __forceinline__ ushort f2bf_rne(float x) {
  uint u = __float_as_uint(x);
  return (ushort)((u + 0x7FFFu + ((u >> 16) & 1u)) >> 16);
}
__device__ __forceinline__ float bf2f(ushort u) {
  return __uint_as_float((uint)u << 16);
}

// ---------------------------------------------------------------------------
// Kernel A: q[b,o] = hsq[b,:] . Wq[o,:] + bq[o]
// ---------------------------------------------------------------------------
__global__ __launch_bounds__(512) void k_q(const float* __restrict__ hsq,
                                           const float* __restrict__ Wq,
                                           const float* __restrict__ bq,
                                           float* __restrict__ q) {
  __shared__ float hs[B * QR];  // 96 KiB
  int tid = threadIdx.x;
  for (int idx = tid * 4; idx < B * QR; idx += 2048)
    *(float4*)&hs[idx] = *(const float4*)&hsq[idx];
  __syncthreads();

  int wave = tid >> 6, lane = tid & 63;
  int o = blockIdx.x * 16 + wave * 2;

  float acc0[B], acc1[B];
#pragma unroll
  for (int b = 0; b < B; ++b) { acc0[b] = 0.f; acc1[b] = 0.f; }

  const float* w0r = Wq + (size_t)o * QR;
  const float* w1r = w0r + QR;
  for (int k = lane * 4; k < QR; k += 256) {
    float4 wa = *(const float4*)&w0r[k];
    float4 wb = *(const float4*)&w1r[k];
#pragma unroll
    for (int b = 0; b < B; ++b) {
      float4 h4 = *(const float4*)&hs[b * QR + k];
      acc0[b] += wa.x * h4.x + wa.y * h4.y + wa.z * h4.z + wa.w * h4.w;
      acc1[b] += wb.x * h4.x + wb.y * h4.y + wb.z * h4.z + wb.w * h4.w;
    }
  }
#pragma unroll
  for (int b = 0; b < B; ++b) {
    float v0 = acc0[b], v1 = acc1[b];
#pragma unroll
    for (int off = 32; off > 0; off >>= 1) {
      v0 += __shfl_xor(v0, off);
      v1 += __shfl_xor(v1, off);
    }
    if (lane == 0) {
      q[b * HD + o]     = v0 + bq[o];
      q[b * HD + o + 1] = v1 + bq[o + 1];
    }
  }
}

// ---------------------------------------------------------------------------
// Kernel B: qhat[b,h,r] = sum_d q[b, h*D+d] * Wkv[h*D+d, r]
// ---------------------------------------------------------------------------
__global__ __launch_bounds__(256) void k_qhat(const float* __restrict__ q,
                                              const float* __restrict__ Wkv,
                                              float* __restrict__ qhat) {
  int h = blockIdx.x;
  int r0 = blockIdx.y * 64;
  __shared__ float qs[B][D];
  int tid = threadIdx.x;
  for (int idx = tid; idx < B * D; idx += 256) {
    int b = idx >> 7, d = idx & (D - 1);
    qs[b][d] = q[b * HD + h * D + d];
  }
  __syncthreads();

  int r_l = tid & 63, bg = tid >> 6;
  float acc[4] = {0.f, 0.f, 0.f, 0.f};
  const float* wbase = Wkv + (size_t)(h * D) * R + r0 + r_l;
  for (int d = 0; d < D; d += 4) {
    float w0 = wbase[(d + 0) * R];
    float w1 = wbase[(d + 1) * R];
    float w2 = wbase[(d + 2) * R];
    float w3 = wbase[(d + 3) * R];
#pragma unroll
    for (int i = 0; i < 4; ++i) {
      float4 q4 = *(const float4*)&qs[bg * 4 + i][d];
      acc[i] += q4.x * w0 + q4.y * w1 + q4.z * w2 + q4.w * w3;
    }
  }
#pragma unroll
  for (int i = 0; i < 4; ++i)
    qhat[((size_t)(bg * 4 + i) * H + h) * R + r0 + r_l] = acc[i];
}

// ---------------------------------------------------------------------------
// Fused MFMA flash kernel v2. grid (B, CH) x 512 threads (8 waves), 2 blk/CU.
// Phase 1: logits[32 h][128 s] = qhat . ckv^T, split-bf16 (3 MFMAs).
//          qhat AND ckv k-tiles staged in LDS (hi/lo, XOR swizzle), with
//          register prefetch of the next tile (T14 async-stage split).
// softmax: in registers + [32][8] cross-wave LDS reduce; P -> Ps (bf16 swz).
// Phase 2: part[64 r][32 h] per rt = ckv^T . P, bf16, register-prefetched
//          transposed restage (L3-hot re-read). part stored bf16.
// q.bkv logit term is constant per (b,h) -> cancels in softmax.
// ---------------------------------------------------------------------------
__global__ __launch_bounds__(512, 4) void k_fmha(const float* __restrict__ qhat,
                                                 const float* __restrict__ ckv,
                                                 ushort* __restrict__ part,
                                                 float* __restrict__ mbuf,
                                                 float* __restrict__ lbuf) {
  // byte map: [0,16K) cs1h | ph2 cs2 ; [16K,32K) cs1l | softmax red ;
  //           [32K,40K) qsh ; [40K,48K) qsl ; Ps separate 8K. total 56 KB.
  __shared__ __align__(16) ushort smem[24576];   // 48 KB
  __shared__ __align__(16) ushort Ps[H * 128];   // 8 KB

  ushort* cs1h = smem;                      // [128 s][64 k] swz
  ushort* cs1l = smem + 8192;
  ushort* qsh  = smem + 16384;              // [32 m][64 k] swz
  ushort* qsl  = smem + 20480;
  float*  redm = (float*)(smem + 8192);     // [32 h][8 w]  (cs1l region, dead)
  float*  redl = redm + 256;                // [32 h][8 w]
  ushort* cs2  = smem;                      // [64 r][128 s] swz (cs1h region)

  const int b = blockIdx.x, chunk = blockIdx.y;
  const int tid = threadIdx.x;
  const int lane = tid & 63, w = tid >> 6;
  const int lcol = lane & 15, lgrp = lane >> 4;
  const float* cbase = ckv + ((size_t)b * S + (size_t)chunk * SC) * R;
  const float* qbase = qhat + (size_t)b * H * R;

  const int st_s = tid >> 2;            // 0..127
  const int st_k = (tid & 3) * 16;      // 0,16,32,48
  const int qrow = tid >> 4;            // 0..31
  const int qk   = (tid & 15) * 4;

  f32x4 acc[2];
  acc[0] = {0.f, 0.f, 0.f, 0.f};
  acc[1] = {0.f, 0.f, 0.f, 0.f};

  // ---------------- phase 1: QK^T ----------------
  float4 v[4], vq;
  {
    const float* src = cbase + (size_t)st_s * R + st_k;
#pragma unroll
    for (int j = 0; j < 4; ++j) v[j] = *(const float4*)(src + 4 * j);
    vq = *(const float4*)(qbase + (size_t)qrow * R + qk);
  }

  for (int kt = 0; kt < R; kt += 64) {
    // write the prefetched tile to LDS (hi/lo)
#pragma unroll
    for (int j = 0; j < 4; ++j) {
      int k0 = st_k + 4 * j;
      int idx = st_s * 64 + (((k0 >> 3) ^ (st_s & 7)) << 3) + (k0 & 7);
      float4 t = v[j];
      *(uint*)&cs1h[idx]     = (uint)bf_hi(t.x) | ((uint)bf_hi(t.y) << 16);
      *(uint*)&cs1h[idx + 2] = (uint)bf_hi(t.z) | ((uint)bf_hi(t.w) << 16);
      *(uint*)&cs1l[idx]     = (uint)bf_hi(bf_res(t.x)) | ((uint)bf_hi(bf_res(t.y)) << 16);
      *(uint*)&cs1l[idx + 2] = (uint)bf_hi(bf_res(t.z)) | ((uint)bf_hi(bf_res(t.w)) << 16);
    }
    {
      int idx = qrow * 64 + (((qk >> 3) ^ (qrow & 7)) << 3) + (qk & 7);
      *(uint*)&qsh[idx]     = (uint)bf_hi(vq.x) | ((uint)bf_hi(vq.y) << 16);
      *(uint*)&qsh[idx + 2] = (uint)bf_hi(vq.z) | ((uint)bf_hi(vq.w) << 16);
      *(uint*)&qsl[idx]     = (uint)bf_hi(bf_res(vq.x)) | ((uint)bf_hi(bf_res(vq.y)) << 16);
      *(uint*)&qsl[idx + 2] = (uint)bf_hi(bf_res(vq.z)) | ((uint)bf_hi(bf_res(vq.w)) << 16);
    }
    __syncthreads();
    // prefetch next tile into registers (latency hides under MFMA section)
    if (kt + 64 < R) {
      const float* src = cbase + (size_t)st_s * R + (kt + 64) + st_k;
#pragma unroll
      for (int j = 0; j < 4; ++j) v[j] = *(const float4*)(src + 4 * j);
      vq = *(const float4*)(qbase + (size_t)qrow * R + (kt + 64) + qk);
    }
#pragma unroll
    for (int ks = 0; ks < 2; ++ks) {
      const int kb = ks * 4 + lgrp;
      s16x8 ah[2], al[2], bh, bl;
#pragma unroll
      for (int mt = 0; mt < 2; ++mt) {
        int m = 16 * mt + lcol;
        int idx = m * 64 + ((kb ^ (m & 7)) << 3);
        ah[mt] = *(s16x8*)&qsh[idx];
        al[mt] = *(s16x8*)&qsl[idx];
      }
      {
        int sf = 16 * w + lcol;
        int idx = sf * 64 + ((kb ^ (sf & 7)) << 3);
        bh = *(s16x8*)&cs1h[idx];
        bl = *(s16x8*)&cs1l[idx];
      }
#pragma unroll
      for (int mt = 0; mt < 2; ++mt) {
        acc[mt] = __builtin_amdgcn_mfma_f32_16x16x32_bf16(ah[mt], bh, acc[mt], 0, 0, 0);
        acc[mt] = __builtin_amdgcn_mfma_f32_16x16x32_bf16(ah[mt], bl, acc[mt], 0, 0, 0);
        acc[mt] = __builtin_amdgcn_mfma_f32_16x16x32_bf16(al[mt], bh, acc[mt], 0, 0, 0);
      }
    }
    __syncthreads();
  }

  // ---------------- softmax (register + cross-wave LDS reduce) ----------------
  // D layout: h = 16*mt + lgrp*4 + i ; s = 16*w + lcol
  float pm[2][4];
#pragma unroll
  for (int mt = 0; mt < 2; ++mt)
#pragma unroll
    for (int i = 0; i < 4; ++i) pm[mt][i] = acc[mt][i];
#pragma unroll
  for (int off = 1; off <= 8; off <<= 1)
#pragma unroll
    for (int mt = 0; mt < 2; ++mt)
#pragma unroll
      for (int i = 0; i < 4; ++i)
        pm[mt][i] = fmaxf(pm[mt][i], __shfl_xor(pm[mt][i], off));
  if (lcol == 0) {
#pragma unroll
    for (int mt = 0; mt < 2; ++mt)
#pragma unroll
      for (int i = 0; i < 4; ++i)
        redm[(16 * mt + lgrp * 4 + i) * 8 + w] = pm[mt][i];
  }
  __syncthreads();

  float e_[2][4], ps[2][4];
#pragma unroll
  for (int mt = 0; mt < 2; ++mt)
#pragma unroll
    for (int i = 0; i < 4; ++i) {
      int h = 16 * mt + lgrp * 4 + i;
      float4 r0 = *(float4*)&redm[h * 8];
      float4 r1 = *(float4*)&redm[h * 8 + 4];
      float m = fmaxf(fmaxf(fmaxf(r0.x, r0.y), fmaxf(r0.z, r0.w)),
                      fmaxf(fmaxf(r1.x, r1.y), fmaxf(r1.z, r1.w)));
      float e = __expf(acc[mt][i] - m);
      e_[mt][i] = e;
      ps[mt][i] = e;
    }
#pragma unroll
  for (int off = 1; off <= 8; off <<= 1)
#pragma unroll
    for (int mt = 0; mt < 2; ++mt)
#pragma unroll
      for (int i = 0; i < 4; ++i)
        ps[mt][i] += __shfl_xor(ps[mt][i], off);
  if (lcol == 0) {
#pragma unroll
    for (int mt = 0; mt < 2; ++mt)
#pragma unroll
      for (int i = 0; i < 4; ++i)
        redl[(16 * mt + lgrp * 4 + i) * 8 + w] = ps[mt][i];
  }
  // P -> Ps (bf16, swizzled)
#pragma unroll
  for (int mt = 0; mt < 2; ++mt)
#pragma unroll
    for (int i = 0; i < 4; ++i) {
      int h = 16 * mt + lgrp * 4 + i;
      int s = 16 * w + lcol;
      Ps[h * 128 + (((s >> 3) ^ (h & 7)) << 3) + (s & 7)] = f2bf_rne(e_[mt][i]);
    }
  __syncthreads();

  if (w == 0 && lcol == 0) {
#pragma unroll
    for (int mt = 0; mt < 2; ++mt)
#pragma unroll
      for (int i = 0; i < 4; ++i) {
        int h = 16 * mt + lgrp * 4 + i;
        float4 r0 = *(float4*)&redm[h * 8];
        float4 r1 = *(float4*)&redm[h * 8 + 4];
        float M = fmaxf(fmaxf(fmaxf(r0.x, r0.y), fmaxf(r0.z, r0.w)),
                        fmaxf(fmaxf(r1.x, r1.y), fmaxf(r1.z, r1.w)));
        float4 l0 = *(float4*)&redl[h * 8];
        float4 l1 = *(float4*)&redl[h * 8 + 4];
        float L = (l0.x + l0.y + l0.z + l0.w) + (l1.x + l1.y + l1.z + l1.w);
        mbuf[((size_t)b * CH + chunk) * H + h] = M;
        lbuf[((size_t)b * CH + chunk) * H + h] = L;
      }
  }

  // ---------------- phase 2: part = P . ckv ----------------
  const int nt = w & 1, mtr = w >> 1;
  s16x8 bp4[4];
#pragma unroll
  for (int kt4 = 0; kt4 < 4; ++kt4) {
    int h = 16 * nt + lcol;
    int kb = kt4 * 4 + lgrp;
    bp4[kt4] = *(s16x8*)&Ps[h * 128 + ((kb ^ (h & 7)) << 3)];
  }

  const int b7 = tid & 7, sp = tid >> 3;  // sp 0..63
  const int s0 = 2 * sp;
  float ra[8], rb[8];
  {
    const float* row0 = cbase + (size_t)s0 * R;
    const float* row1 = row0 + R;
#pragma unroll
    for (int i = 0; i < 8; ++i) { ra[i] = row0[b7 + 8 * i]; rb[i] = row1[b7 + 8 * i]; }
  }
  ushort* pb = part + (size_t)(b * CH + chunk) * H * R;

  for (int rt = 0; rt < 8; ++rt) {
    // write prefetched transposed tile
#pragma unroll
    for (int i = 0; i < 8; ++i) {
      int r = b7 + 8 * i;
      int idx = r * 128 + (((s0 >> 3) ^ (r & 7)) << 3) + (s0 & 7);
      *(uint*)&cs2[idx] = (uint)f2bf_rne(ra[i]) | ((uint)f2bf_rne(rb[i]) << 16);
    }
    __syncthreads();
    if (rt < 7) {
      const float* row0 = cbase + (size_t)s0 * R + (rt + 1) * 64;
      const float* row1 = row0 + R;
#pragma unroll
      for (int i = 0; i < 8; ++i) { ra[i] = row0[b7 + 8 * i]; rb[i] = row1[b7 + 8 * i]; }
    }
    f32x4 acc2 = {0.f, 0.f, 0.f, 0.f};
    const int rl = 16 * mtr + lcol;
#pragma unroll
    for (int kt4 = 0; kt4 < 4; ++kt4) {
      int kb = kt4 * 4 + lgrp;
      s16x8 a2 = *(s16x8*)&cs2[rl * 128 + ((kb ^ (rl & 7)) << 3)];
      acc2 = __builtin_amdgcn_mfma_f32_16x16x32_bf16(a2, bp4[kt4], acc2, 0, 0, 0);
    }
    {
      int h = 16 * nt + lcol;
#pragma unroll
      for (int i = 0; i < 4; ++i) {
        int rg = rt * 64 + 16 * mtr + lgrp * 4 + i;
        pb[(size_t)h * R + rg] = f2bf_rne(acc2[i]);
      }
    }
    __syncthreads();
  }
}

// ---------------------------------------------------------------------------
// Combine: ctx[b,h,r] = sum_c e^{m_c-M} part[b,c,h,r] / sum_c e^{m_c-M} l_c
// ---------------------------------------------------------------------------
__global__ __launch_bounds__(256) void k_combine(const ushort* __restrict__ part,
                                                 const float* __restrict__ mbuf,
                                                 const float* __restrict__ lbuf,
                                                 float* __restrict__ ctx) {
  const int bid = blockIdx.x;
  const int b = bid >> 5, h = bid & 31;
  const int tid = threadIdx.x;
  float mv[CH], wv[CH];
  float M = -3.0e38f;
#pragma unroll
  for (int c = 0; c < CH; ++c) {
    mv[c] = mbuf[((size_t)b * CH + c) * H + h];
    M = fmaxf(M, mv[c]);
  }
  float denom = 0.f;
#pragma unroll
  for (int c = 0; c < CH; ++c) {
    wv[c] = __expf(mv[c] - M);
    denom += wv[c] * lbuf[((size_t)b * CH + c) * H + h];
  }
  const float inv = 1.f / denom;
  float s0 = 0.f, s1 = 0.f;
#pragma unroll
  for (int c = 0; c < CH; ++c) {
    const ushort* pp = part + (((size_t)b * CH + c) * H + h) * R;
    s0 += wv[c] * bf2f(pp[tid]);
    s1 += wv[c] * bf2f(pp[tid + 256]);
  }
  ctx[((size_t)b * H + h) * R + tid] = s0 * inv;
  ctx[((size_t)b * H + h) * R + tid + 256] = s1 * inv;
}

// ---------------------------------------------------------------------------
// Kernel F2: out[b, h*D+d] = Wkv[h*D+d,:] . ctx[b,h,:] + bkv[h*D+d]
// ---------------------------------------------------------------------------
__global__ __launch_bounds__(256) void k_out(const float* __restrict__ ctx,
                                             const float* __restrict__ Wkv,
                                             const float* __restrict__ bkv,
                                             float* __restrict__ out) {
  int h = blockIdx.x;
  int d0 = blockIdx.y * 32;
  __shared__ float cs[B][R];  // 32 KiB
  int tid = threadIdx.x;
  for (int idx = tid * 4; idx < B * R; idx += 1024) {
    int b = idx >> 9, r = idx & 511;
    *(float4*)&cs[b][r] = *(const float4*)&ctx[(size_t)(b * H + h) * R + r];
  }
  __syncthreads();

  int dg = tid & 31;
  int bg = tid >> 5;
  int d = d0 + dg;
  int b0 = bg * 2;
  float acc0 = 0.f, acc1 = 0.f;
  const float* wrow = Wkv + ((size_t)(h * D + d)) * R;
  for (int i = 0; i < R; i += 4) {
    float4 w4 = *(const float4*)&wrow[i];
    float4 ca = *(const float4*)&cs[b0][i];
    float4 cb = *(const float4*)&cs[b0 + 1][i];
    acc0 += w4.x * ca.x + w4.y * ca.y + w4.z * ca.z + w4.w * ca.w;
    acc1 += w4.x * cb.x + w4.y * cb.y + w4.z * cb.z + w4.w * cb.w;
  }
  float bv = bkv[h * D + d];
  out[(size_t)b0 * HD + h * D + d]       = acc0 + bv;
  out[(size_t)(b0 + 1) * HD + h * D + d] = acc1 + bv;
}

// ---------------------------------------------------------------------------
extern "C" void kernel_launch(void* const* d_in, const int* in_sizes, int n_in,
                              void* d_out, int out_size, void* d_ws, size_t ws_size,
                              hipStream_t stream) {
  (void)in_sizes; (void)n_in; (void)out_size; (void)ws_size;
  const float* hsq = (const float*)d_in[0];
  const float* ckv = (const float*)d_in[1];
  const float* Wq  = (const float*)d_in[2];
  const float* bq  = (const float*)d_in[3];
  const float* Wkv = (const float*)d_in[4];
  const float* bkv = (const float*)d_in[5];
  float* out = (float*)d_out;

  float* ws   = (float*)d_ws;
  float* q    = ws;                          // 65536 f
  float* qhat = q + 65536;                   // 262144 f
  float* ctx  = qhat + 262144;               // 262144 f
  float* mbuf = ctx + 262144;                // 16384 f
  float* lbuf = mbuf + (size_t)B * CH * H;   // 16384 f
  ushort* part = (ushort*)(lbuf + (size_t)B * CH * H);  // B*CH*H*R bf16 = 16 MB

  k_q<<<256, 512, 0, stream>>>(hsq, Wq, bq, q);
  k_qhat<<<dim3(32, 8), 256, 0, stream>>>(q, Wkv, qhat);
  k_fmha<<<dim3(B, CH), 512, 0, stream>>>(qhat, ckv, part, mbuf, lbuf);
  k_combine<<<B * H, 256, 0, stream>>>(part, mbuf, lbuf, ctx);
  k_out<<<dim3(32, 4), 256, 0, stream>>>(ctx, Wkv, bkv, out);
}